// Round 9
// baseline (145.707 us; speedup 1.0000x reference)
//
#include <hip/hip_runtime.h>

// input_: (B=64, 2*N=16384, 2, 2, 16) f32 ; diag1/2: (N=8192, 2, 2, 8) f32
// out: (B, N, 2, 2, 23) f32
//   out[b,n,i,j,:] = sum_k conv(x1[b,n,i,k,:], d1[n,k,j,:]) + (x2, d2)
//
// Round 9: pipelined multi-tile blocks. Rounds 6/7/8 all plateau at 88-93 us
// across very different occupancy points -> NOT TLP-limited; the gap to the
// ~71 us copy roofline is read-stream starvation during each block's
// compute/store phases. Fix: 2048 blocks x 4 consecutive tiles; half-tile
// register prefetch (4 float4 = 16 regs, keeps VGPR under the 128 cliff):
//   write x1(t)->LDS | issue x2(t) | compute1 | write x2->LDS |
//   issue x1(t+1) | compute2 | stage+store out   <- loads in flight throughout
// TILE=64, 16 KB LDS reused x-half -> out staging (two 32-unit store passes).
// No launch_bounds min-waves hint (rounds 3/5: forces catastrophic spills).
#define BB 64
#define NN 8192
#define TILE 64
#define DOUT 23
#define TPB 4  // consecutive tiles per block (same b: 128 ntiles % 4 == 0)

__device__ __forceinline__ int swz(int G) { return G ^ ((G >> 3) & 7); }

__device__ __forceinline__ void compute_half(const float4* __restrict__ sbuf,
                                             const float4* __restrict__ dp,
                                             int unit, int i, float* __restrict__ acc) {
#pragma unroll
    for (int k = 0; k < 2; ++k) {
        float4 dq0 = dp[k * 4 + 0], dq1 = dp[k * 4 + 1];
        const float dv[8] = {dq0.x, dq0.y, dq0.z, dq0.w,
                             dq1.x, dq1.y, dq1.z, dq1.w};
#pragma unroll
        for (int q = 0; q < 4; ++q) {
            float4 xq = sbuf[swz(unit * 16 + i * 8 + k * 4 + q)];
            const float xe[4] = {xq.x, xq.y, xq.z, xq.w};
#pragma unroll
            for (int e = 0; e < 4; ++e) {
#pragma unroll
                for (int v = 0; v < 8; ++v) {
                    acc[q * 4 + e + v] += xe[e] * dv[v];
                }
            }
        }
    }
}

__global__ __launch_bounds__(256) void hstackdiag_kernel(
    const float* __restrict__ input,
    const float* __restrict__ diag1,
    const float* __restrict__ diag2,
    float* __restrict__ out) {
    __shared__ float4 sbuf[1024];  // 16 KB: x half-tile, reused for out staging

    const int t = threadIdx.x;
    const int tile0 = blockIdx.x * TPB;      // 4 consecutive tiles, same b
    const int b = tile0 >> 7;                // 128 ntiles per b
    const int j = t & 1;
    const int i = (t >> 1) & 1;
    const int unit = t >> 2;

    const float4* gbase = (const float4*)input + (size_t)b * (2 * NN) * 16;
    int n0 = (tile0 & 127) * TILE;

    // Prologue: R <- x1(tile0). 4 coalesced float4 loads (16 KB half-tile).
    float4 R[4];
    {
        const float4* g1 = gbase + (size_t)n0 * 16;
#pragma unroll
        for (int r = 0; r < 4; ++r) R[r] = g1[r * 256 + t];
    }

    for (int tt = 0; tt < TPB; ++tt) {
        const int n = n0 + unit;
        const float4* dp1 = (const float4*)diag1 + (size_t)n * 8 + j * 2;
        const float4* dp2 = (const float4*)diag2 + (size_t)n * 8 + j * 2;

        __syncthreads();  // prev tile's store pass done reading sbuf
#pragma unroll
        for (int r = 0; r < 4; ++r) sbuf[swz(r * 256 + t)] = R[r];
        __syncthreads();
        {   // issue x2(tt) — in flight during compute half 1
            const float4* g2 = gbase + (size_t)(NN + n0) * 16;
#pragma unroll
            for (int r = 0; r < 4; ++r) R[r] = g2[r * 256 + t];
        }

        float acc[DOUT];
#pragma unroll
        for (int u = 0; u < DOUT; ++u) acc[u] = 0.0f;
        compute_half(sbuf, dp1, unit, i, acc);

        __syncthreads();  // all waves done reading x1
#pragma unroll
        for (int r = 0; r < 4; ++r) sbuf[swz(r * 256 + t)] = R[r];
        __syncthreads();
        if (tt < TPB - 1) {  // issue x1(tt+1) — in flight through compute2+stores
            const float4* g1n = gbase + (size_t)(n0 + TILE) * 16;
#pragma unroll
            for (int r = 0; r < 4; ++r) R[r] = g1n[r * 256 + t];
        }
        compute_half(sbuf, dp2, unit, i, acc);

        __syncthreads();  // x2 reads done; reuse sbuf for output staging

        // Output tile: 64 units * 92 floats, two passes of 32 units
        // (2944 floats = 736 float4 = 2*256 + 224 per pass).
        float* sout = (float*)sbuf;
        float4* sout4 = sbuf;
        float* gout = out + ((size_t)b * NN + n0) * (4 * DOUT);
        const int c = i * 2 + j;
#pragma unroll
        for (int p = 0; p < 2; ++p) {
            if ((unit >> 5) == p) {
#pragma unroll
                for (int q = 0; q < DOUT; ++q)
                    sout[(unit & 31) * 92 + c * DOUT + q] = acc[q];
            }
            __syncthreads();
            float4* g4 = (float4*)(gout + p * 2944);  // 16B-aligned: 92|2944 %4==0
#pragma unroll
            for (int rr = 0; rr < 2; ++rr) g4[rr * 256 + t] = sout4[rr * 256 + t];
            if (t < 224) g4[512 + t] = sout4[512 + t];
            if (p == 0) __syncthreads();  // pass-0 copies done before pass-1 staging
        }
        n0 += TILE;
    }
}

extern "C" void kernel_launch(void* const* d_in, const int* in_sizes, int n_in,
                              void* d_out, int out_size, void* d_ws, size_t ws_size,
                              hipStream_t stream) {
    const float* input = (const float*)d_in[0];
    const float* diag1 = (const float*)d_in[1];
    const float* diag2 = (const float*)d_in[2];
    float* out = (float*)d_out;

    const int grid = BB * (NN / TILE) / TPB;  // 8192 tiles / 4 = 2048 blocks
    hstackdiag_kernel<<<grid, 256, 0, stream>>>(input, diag1, diag2, out);
}

// Round 10
// 100.751 us; speedup vs baseline: 1.4462x; 1.4462x over previous
//
#include <hip/hip_runtime.h>
#include <stdint.h>

// input_: (B=64, 2*N=16384, 2, 2, 16) f32 ; diag1/2: (N=8192, 2, 2, 8) f32
// out: (B, N, 2, 2, 23) f32
//   out[b,n,i,j,:] = sum_k conv(x1[b,n,i,k,:], d1[n,k,j,:]) + (x2, d2)
//
// Round 10: always-on read stream with ZERO prefetch registers.
// Round 9 proved the compiler spills register-carried prefetch state
// (VGPR=52 + 221 MB scratch writes). Fix: prefetch via global_load_lds
// (direct HBM->LDS DMA, no VGPR round-trip). Double-buffered 16 KB
// half-tiles A/B (32 KB -> 5 blocks/CU, same as the 88 us champion):
//   top barrier | gll x2(t)->B | compute1(A) | barrier (B ready)
//   | gll x1(t+1)->A | compute2(B) | barrier | out-stage in B | stores
// Every vmcnt-drain (implicit before each s_barrier) sits AFTER a full
// compute phase -> load latency always hidden; reads in flight during
// the store phase too. LDS dest of gll is linear (m104), so the XOR
// bank-swizzle is applied to the per-lane GLOBAL source address (m173);
// swz is an involution so src_chunk = swz(dest_chunk).
#define BB 64
#define NN 8192
#define TILE 64
#define DOUT 23
#define TPB 4  // consecutive tiles per block (same b: 128 % 4 == 0)

__device__ __forceinline__ int swz(int G) { return G ^ ((G >> 3) & 7); }

typedef const __attribute__((address_space(1))) uint32_t* gas_u32p;
typedef __attribute__((address_space(3))) uint32_t* las_u32p;

// Stage one 16 KB half-tile (1024 float4 chunks) gsrc -> dst via
// global_load_lds. Dest is linear: wave w, issue r covers chunks
// [(r*4+w)*64, +64), lane l -> chunk C=(r*4+w)*64+l. Source pre-swizzled.
__device__ __forceinline__ void stage_gll(const float4* __restrict__ gsrc,
                                          float4* dst, int w, int lane) {
#pragma unroll
    for (int r = 0; r < 4; ++r) {
        const int C = (r * 4 + w) * 64 + lane;
        const int S = swz(C);
        __builtin_amdgcn_global_load_lds((gas_u32p)(const void*)(gsrc + S),
                                         (las_u32p)(void*)(dst + (r * 4 + w) * 64),
                                         16, 0, 0);
    }
}

__device__ __forceinline__ void compute_half(const float4* __restrict__ buf,
                                             const float4* __restrict__ dp,
                                             int unit, int i, float* __restrict__ acc) {
#pragma unroll
    for (int k = 0; k < 2; ++k) {
        float4 dq0 = dp[k * 4 + 0], dq1 = dp[k * 4 + 1];
        const float dv[8] = {dq0.x, dq0.y, dq0.z, dq0.w,
                             dq1.x, dq1.y, dq1.z, dq1.w};
#pragma unroll
        for (int q = 0; q < 4; ++q) {
            float4 xq = buf[swz(unit * 16 + i * 8 + k * 4 + q)];
            const float xe[4] = {xq.x, xq.y, xq.z, xq.w};
#pragma unroll
            for (int e = 0; e < 4; ++e) {
#pragma unroll
                for (int v = 0; v < 8; ++v) {
                    acc[q * 4 + e + v] += xe[e] * dv[v];
                }
            }
        }
    }
}

__global__ __launch_bounds__(256) void hstackdiag_kernel(
    const float* __restrict__ input,
    const float* __restrict__ diag1,
    const float* __restrict__ diag2,
    float* __restrict__ out) {
    __shared__ float4 bufA[1024];  // 16 KB x half-tile (double buffer)
    __shared__ float4 bufB[1024];  // 16 KB; also reused for out staging

    const int t = threadIdx.x;
    const int lane = t & 63;
    const int w = t >> 6;
    const int tile0 = blockIdx.x * TPB;
    const int b = tile0 >> 7;            // 128 ntiles per b
    int n0 = (tile0 & 127) * TILE;

    const int j = t & 1;
    const int i = (t >> 1) & 1;
    const int unit = t >> 2;

    const float4* gbase = (const float4*)input + (size_t)b * (2 * NN) * 16;

    // Prologue: x1(tile0) -> A (drained by the first top-of-loop barrier).
    stage_gll(gbase + (size_t)n0 * 16, bufA, w, lane);

    for (int tt = 0; tt < TPB; ++tt) {
        const int n = n0 + unit;
        const float4* dp1 = (const float4*)diag1 + (size_t)n * 8 + j * 2;
        const float4* dp2 = (const float4*)diag2 + (size_t)n * 8 + j * 2;

        __syncthreads();  // A ready; prev tile's stores done reading B
        stage_gll(gbase + (size_t)(NN + n0) * 16, bufB, w, lane);  // x2(t)->B

        float acc[DOUT];
#pragma unroll
        for (int u = 0; u < DOUT; ++u) acc[u] = 0.0f;

        compute_half(bufA, dp1, unit, i, acc);   // reads A, hides B-fill

        __syncthreads();  // drains x2 -> B ready; all waves done reading A
        if (tt < TPB - 1)
            stage_gll(gbase + (size_t)(n0 + TILE) * 16, bufA, w, lane);  // x1(t+1)->A

        compute_half(bufB, dp2, unit, i, acc);   // reads B, hides A-fill

        __syncthreads();  // all waves done reading B; reuse B for out staging
        // (also drains the A-fill -- latency was covered by compute2)

        // Out tile: 64 units * 92 floats, two passes of 32 units
        // (2944 floats = 736 float4 = 2*256 + 224 per pass).
        float* sout = (float*)bufB;
        float4* sout4 = bufB;
        float* gout = out + ((size_t)b * NN + n0) * (4 * DOUT);
        const int c = i * 2 + j;
#pragma unroll
        for (int p = 0; p < 2; ++p) {
            if ((unit >> 5) == p) {  // t>>7: wave-uniform
#pragma unroll
                for (int q = 0; q < DOUT; ++q)
                    sout[(unit & 31) * 92 + c * DOUT + q] = acc[q];
            }
            __syncthreads();
            float4* g4 = (float4*)(gout + p * 2944);  // 16B-aligned (92%4==0)
#pragma unroll
            for (int rr = 0; rr < 2; ++rr) g4[rr * 256 + t] = sout4[rr * 256 + t];
            if (t < 224) g4[512 + t] = sout4[512 + t];
            if (p == 0) __syncthreads();  // pass-0 copies read before pass-1 staging
        }
        n0 += TILE;
    }
}

extern "C" void kernel_launch(void* const* d_in, const int* in_sizes, int n_in,
                              void* d_out, int out_size, void* d_ws, size_t ws_size,
                              hipStream_t stream) {
    const float* input = (const float*)d_in[0];
    const float* diag1 = (const float*)d_in[1];
    const float* diag2 = (const float*)d_in[2];
    float* out = (float*)d_out;

    const int grid = BB * (NN / TILE) / TPB;  // 8192 tiles / 4 = 2048 blocks
    hstackdiag_kernel<<<grid, 256, 0, stream>>>(input, diag1, diag2, out);
}